// Round 8
// baseline (393.037 us; speedup 1.0000x reference)
//
#include <hip/hip_runtime.h>

#define NN 100000
#define NE 1600000
#define HF 128
#define NC 64
#define AP 136      // padded LDS row (bf16 elems): 272B stride, 16B-aligned chunks
#define NB 391      // edge buckets: ceil(100000/256)
#define BSH 8       // 256 nodes per bucket
#define BMASK 255
#define BCAP 4608   // fixed bucket capacity (mean 4096 + 8 sigma)

typedef __bf16 bf16x8 __attribute__((ext_vector_type(8)));
typedef float  f32x4  __attribute__((ext_vector_type(4)));
typedef unsigned short us8 __attribute__((ext_vector_type(8)));

__device__ __forceinline__ unsigned short f2b(float x) {
  unsigned int u = __float_as_uint(x);
  u += 0x7FFFu + ((u >> 16) & 1u);   // RNE
  return (unsigned short)(u >> 16);
}
__device__ __forceinline__ float b2f(unsigned short b) {
  return __uint_as_float(((unsigned int)b) << 16);
}

// ---------------- prologue: cast x->bf16, swizzle weights, init gcur ----------
// wt layout (ushort):  ((((ls)*4 + k0)*8 + nt)*64 + q*16 + m)*8 + j
// wtf layout (ushort): (((k0)*4 + nt)*64 + q*16 + m)*8 + j
__global__ __launch_bounds__(256) void prologue(const float* __restrict__ x,
                                                unsigned short* __restrict__ xb,
                                                const float* __restrict__ conv_w,
                                                const float* __restrict__ conv_b,
                                                const float* __restrict__ bn_g,
                                                const float* __restrict__ bn_b,
                                                const float* __restrict__ bn_m,
                                                const float* __restrict__ bn_v,
                                                const float* __restrict__ fc_w,
                                                unsigned short* __restrict__ wt,
                                                unsigned short* __restrict__ wtf,
                                                float* __restrict__ sarr,
                                                float* __restrict__ tarr,
                                                int* __restrict__ gcur) {
  int idx = blockIdx.x * 256 + threadIdx.x;       // grid 6250*256 = 1.6M
  {
    size_t i = (size_t)idx * 8;
    float4 a = *(const float4*)(x + i);
    float4 b = *(const float4*)(x + i + 4);
    us8 v = { f2b(a.x), f2b(a.y), f2b(a.z), f2b(a.w),
              f2b(b.x), f2b(b.y), f2b(b.z), f2b(b.w) };
    *(us8*)(xb + i) = v;
  }
  if (idx < 6 * HF * HF) {
    int j  = idx & 7;
    int m  = (idx >> 3) & 15;
    int q  = (idx >> 7) & 3;
    int nt = (idx >> 9) & 7;
    int k0 = (idx >> 12) & 3;
    int ls = idx >> 14;                 // 0..5
    int k = k0 * 32 + q * 8 + j;
    int n = nt * 16 + m;
    wt[idx] = f2b(conv_w[(ls * HF + k) * HF + n]);
  }
  if (idx < HF * NC) {
    int j  = idx & 7;
    int m  = (idx >> 3) & 15;
    int q  = (idx >> 7) & 3;
    int nt = (idx >> 9) & 3;
    int k0 = idx >> 11;                 // 0..3
    int k = k0 * 32 + q * 8 + j;
    int c = nt * 16 + m;
    wtf[idx] = f2b(fc_w[k * NC + c]);
  }
  if (idx < 6 * HF) {
    float s = bn_g[idx] * rsqrtf(bn_v[idx] + 1e-5f);
    sarr[idx] = s;
    tarr[idx] = (conv_b[idx] - bn_m[idx]) * s + bn_b[idx];
  }
  if (idx < NB) gcur[idx] = idx * BCAP;
}

// ---------------- bin edges into fixed-capacity buckets (single read pass) ----
// entry = src (17 bits) | dst_local (8 bits) << 17
__global__ __launch_bounds__(512) void bin_edges(const int* __restrict__ src,
                                                 const int* __restrict__ dst,
                                                 int* __restrict__ gcur,
                                                 unsigned int* __restrict__ binned) {
  __shared__ int hist[NB];
  int t = threadIdx.x;
  if (t < NB) hist[t] = 0;
  __syncthreads();
  int base = blockIdx.x * 4096;
  int sv[8], dv[8];
  #pragma unroll
  for (int j = 0; j < 8; j++) {
    int e = base + j * 512 + t;
    bool ok = e < NE;
    dv[j] = ok ? dst[e] : -1;
    sv[j] = ok ? src[e] : 0;
    if (ok) atomicAdd(&hist[dv[j] >> BSH], 1);
  }
  __syncthreads();
  if (t < NB) {
    int c = hist[t];
    if (c) hist[t] = atomicAdd(&gcur[t], c);
  }
  __syncthreads();
  #pragma unroll
  for (int j = 0; j < 8; j++) {
    if (dv[j] >= 0) {
      int b = dv[j] >> BSH;
      int p = atomicAdd(&hist[b], 1);
      binned[p] = (unsigned int)sv[j] | ((unsigned int)(dv[j] & BMASK) << 17);
    }
  }
}

// ---------------- per-bucket CSR build: offs + deg + csr (L2-local scatter) ----
__global__ __launch_bounds__(512) void build_csr(const unsigned int* __restrict__ binned,
                                                 const int* __restrict__ gcur,
                                                 int* __restrict__ offs,
                                                 int* __restrict__ deg,
                                                 int* __restrict__ csr) {
  __shared__ int ncnt[256];
  __shared__ int sm[256];
  int t = threadIdx.x;
  int b = blockIdx.x;
  int beg = b * BCAP;
  int cntb = gcur[b] - beg;
  if (t < 256) ncnt[t] = 0;
  __syncthreads();
  for (int e = beg + t; e < beg + cntb; e += 512) atomicAdd(&ncnt[binned[e] >> 17], 1);
  __syncthreads();
  int s = 0;
  if (t < 256) { s = ncnt[t]; sm[t] = s; }
  __syncthreads();
  for (int off = 1; off < 256; off <<= 1) {
    int u = (t < 256 && t >= off) ? sm[t - off] : 0;
    __syncthreads();
    if (t < 256) sm[t] += u;
    __syncthreads();
  }
  if (t < 256) {
    int ex = sm[t] - s + beg;
    int node = (b << BSH) + t;
    if (node < NN) { offs[node] = ex; deg[node] = s; }
    ncnt[t] = ex;
  }
  __syncthreads();
  for (int e = beg + t; e < beg + cntb; e += 512) {
    unsigned int u = binned[e];
    int p = atomicAdd(&ncnt[u >> 17], 1);
    csr[p] = (int)(u & 0x1FFFFu);
  }
}

// ---------------- aggregation: hsum[i] = h[i] + sum_{e->i} h[src_e]  (bf16) ----
// 2-way unrolled edge loop: two outstanding 256B row loads per stream.
__global__ __launch_bounds__(256) void aggregate(const unsigned short* __restrict__ h,
                                                 const int* __restrict__ offs,
                                                 const int* __restrict__ deg,
                                                 const int* __restrict__ csr,
                                                 unsigned short* __restrict__ out) {
  int wave = threadIdx.x >> 6;
  int lane = threadIdx.x & 63;
  int node = blockIdx.x * 4 + wave;
  if (node >= NN) return;
  int g  = lane >> 4;     // edge stream 0..3
  int sl = lane & 15;     // 16B column chunk
  int beg = offs[node];
  int dg  = deg[node];

  float acc[8];
  if (g == 0) {
    us8 v = *(const us8*)(h + (size_t)node * HF + sl * 8);
    #pragma unroll
    for (int i = 0; i < 8; i++) acc[i] = b2f(v[i]);
  } else {
    #pragma unroll
    for (int i = 0; i < 8; i++) acc[i] = 0.f;
  }

  int e = beg + g;
  int last = beg + dg;
  for (; e + 4 < last; e += 8) {          // unroll x2: both loads in flight
    int s0 = csr[e];
    int s1 = csr[e + 4];
    us8 v0 = *(const us8*)(h + (size_t)s0 * HF + sl * 8);
    us8 v1 = *(const us8*)(h + (size_t)s1 * HF + sl * 8);
    #pragma unroll
    for (int i = 0; i < 8; i++) acc[i] += b2f(v0[i]);
    #pragma unroll
    for (int i = 0; i < 8; i++) acc[i] += b2f(v1[i]);
  }
  if (e < last) {
    int s0 = csr[e];
    us8 v0 = *(const us8*)(h + (size_t)s0 * HF + sl * 8);
    #pragma unroll
    for (int i = 0; i < 8; i++) acc[i] += b2f(v0[i]);
  }

  #pragma unroll
  for (int i = 0; i < 8; i++) {
    acc[i] += __shfl_xor(acc[i], 16, 64);
    acc[i] += __shfl_xor(acc[i], 32, 64);
  }
  if (g == 0) {
    us8 r;
    #pragma unroll
    for (int i = 0; i < 8; i++) r[i] = f2b(acc[i]);
    *(us8*)(out + (size_t)node * HF + sl * 8) = r;
  }
}

// =======================================================================
// Barrier-free MLP, 32 rows/wave (2 row-tiles share each B fragment):
// weights direct from global (fragment-swizzled, L1/L2-resident);
// activations wave-private (global -> regs -> LDS own rows).
// =======================================================================
__device__ __forceinline__ void mlp3_body(const unsigned short* __restrict__ in,
                                          unsigned short* Ab,
                                          const unsigned short* __restrict__ wt,
                                          const float* __restrict__ sarr,
                                          const float* __restrict__ tarr,
                                          int layer, int row0, int wave, int lane,
                                          bf16x8 af[2][4]) {
  int m = lane & 15, q = lane >> 4;
  #pragma unroll
  for (int rt = 0; rt < 2; rt++) {
    int node = row0 + wave * 32 + rt * 16 + m;
    int nclamp = (node < NN) ? node : 0;      // OOB rows compute garbage, never stored
    #pragma unroll
    for (int k0 = 0; k0 < 4; k0++)
      af[rt][k0] = *(const bf16x8*)(in + (size_t)nclamp * HF + k0 * 32 + q * 8);
  }

  const unsigned short* wbase = wt + layer * 3 * 16384;
  #pragma unroll
  for (int sub = 0; sub < 3; sub++) {
    const unsigned short* wsub = wbase + sub * 16384;
    f32x4 acc[2][8];
    #pragma unroll
    for (int nt = 0; nt < 8; nt++) {
      acc[0][nt] = (f32x4){0.f, 0.f, 0.f, 0.f};
      acc[1][nt] = (f32x4){0.f, 0.f, 0.f, 0.f};
      #pragma unroll
      for (int k0 = 0; k0 < 4; k0++) {
        bf16x8 bf = *(const bf16x8*)(wsub + ((k0 * 8 + nt) * 64 + lane) * 8);
        acc[0][nt] = __builtin_amdgcn_mfma_f32_16x16x32_bf16(af[0][k0], bf, acc[0][nt], 0, 0, 0);
        acc[1][nt] = __builtin_amdgcn_mfma_f32_16x16x32_bf16(af[1][k0], bf, acc[1][nt], 0, 0, 0);
      }
    }
    const float* sp = sarr + (layer * 3 + sub) * HF;
    const float* tp = tarr + (layer * 3 + sub) * HF;
    #pragma unroll
    for (int nt = 0; nt < 8; nt++) {
      int c = nt * 16 + m;
      float sc = sp[c], sh = tp[c];
      #pragma unroll
      for (int rt = 0; rt < 2; rt++) {
        #pragma unroll
        for (int i = 0; i < 4; i++) {
          int r = wave * 32 + rt * 16 + q * 4 + i;  // C/D: col=lane&15, row=(lane>>4)*4+i
          float y = fmaxf(acc[rt][nt][i] * sc + sh, 0.f);
          Ab[r * AP + c] = f2b(y);                  // own rows: no barrier
        }
      }
    }
    #pragma unroll
    for (int rt = 0; rt < 2; rt++)
      #pragma unroll
      for (int k0 = 0; k0 < 4; k0++)        // reload fragments (wave-local LDS RAW)
        af[rt][k0] = *(const bf16x8*)&Ab[(wave * 32 + rt * 16 + m) * AP + k0 * 32 + q * 8];
  }
}

// ---------------- layer-0 MLP: bf16 in -> bf16 out ----------------
__global__ __launch_bounds__(256) void mlp3(const unsigned short* __restrict__ in,
                                            unsigned short* __restrict__ out,
                                            const unsigned short* __restrict__ wt,
                                            const float* __restrict__ sarr,
                                            const float* __restrict__ tarr) {
  __shared__ unsigned short Ab[128 * AP];
  int t = threadIdx.x;
  int lane = t & 63, wave = t >> 6;
  int row0 = blockIdx.x * 128;
  bf16x8 af[2][4];
  mlp3_body(in, Ab, wt, sarr, tarr, 0, row0, wave, lane, af);

  // wave-local coalesced bf16 store of own 32 rows
  for (int it = 0; it < 8; it++) {
    int idx = it * 64 + lane;              // 4 rows x 16 chunks per pass
    int r = wave * 32 + (idx >> 4);
    int c = (idx & 15) << 3;
    int gr = row0 + r;
    if (gr < NN) *(us8*)(out + (size_t)gr * HF + c) = *(const us8*)&Ab[r * AP + c];
  }
}

// ---------------- layer-1 MLP + FC(128->64) + log_softmax ----------------
__global__ __launch_bounds__(256) void mlp3fc(const unsigned short* __restrict__ in,
                                              float* __restrict__ out,
                                              const unsigned short* __restrict__ wt,
                                              const float* __restrict__ sarr,
                                              const float* __restrict__ tarr,
                                              const unsigned short* __restrict__ wtf,
                                              const float* __restrict__ fc_b) {
  __shared__ unsigned short Ab[128 * AP];
  int t = threadIdx.x;
  int lane = t & 63, wave = t >> 6;
  int row0 = blockIdx.x * 128;
  int m = lane & 15, q = lane >> 4;
  bf16x8 af[2][4];
  mlp3_body(in, Ab, wt, sarr, tarr, 1, row0, wave, lane, af);

  // ---- FC 128->64 + log_softmax, all in registers ----
  f32x4 acc[2][4];
  #pragma unroll
  for (int nt = 0; nt < 4; nt++) {
    acc[0][nt] = (f32x4){0.f, 0.f, 0.f, 0.f};
    acc[1][nt] = (f32x4){0.f, 0.f, 0.f, 0.f};
    #pragma unroll
    for (int k0 = 0; k0 < 4; k0++) {
      bf16x8 bf = *(const bf16x8*)(wtf + ((k0 * 4 + nt) * 64 + lane) * 8);
      acc[0][nt] = __builtin_amdgcn_mfma_f32_16x16x32_bf16(af[0][k0], bf, acc[0][nt], 0, 0, 0);
      acc[1][nt] = __builtin_amdgcn_mfma_f32_16x16x32_bf16(af[1][k0], bf, acc[1][nt], 0, 0, 0);
    }
  }
  #pragma unroll
  for (int rt = 0; rt < 2; rt++) {
    float v[4][4];
    #pragma unroll
    for (int nt = 0; nt < 4; nt++) {
      float b = fc_b[nt * 16 + m];
      #pragma unroll
      for (int i = 0; i < 4; i++) v[nt][i] = acc[rt][nt][i] + b;
    }
    float mx[4], sum[4];
    #pragma unroll
    for (int i = 0; i < 4; i++) {
      mx[i] = fmaxf(fmaxf(v[0][i], v[1][i]), fmaxf(v[2][i], v[3][i]));
      mx[i] = fmaxf(mx[i], __shfl_xor(mx[i], 1, 64));
      mx[i] = fmaxf(mx[i], __shfl_xor(mx[i], 2, 64));
      mx[i] = fmaxf(mx[i], __shfl_xor(mx[i], 4, 64));
      mx[i] = fmaxf(mx[i], __shfl_xor(mx[i], 8, 64));
      sum[i] = __expf(v[0][i] - mx[i]) + __expf(v[1][i] - mx[i])
             + __expf(v[2][i] - mx[i]) + __expf(v[3][i] - mx[i]);
      sum[i] += __shfl_xor(sum[i], 1, 64);
      sum[i] += __shfl_xor(sum[i], 2, 64);
      sum[i] += __shfl_xor(sum[i], 4, 64);
      sum[i] += __shfl_xor(sum[i], 8, 64);
      sum[i] = __logf(sum[i]) + mx[i];     // logsumexp
    }
    #pragma unroll
    for (int i = 0; i < 4; i++) {
      int gr = row0 + wave * 32 + rt * 16 + q * 4 + i;
      if (gr < NN) {
        #pragma unroll
        for (int nt = 0; nt < 4; nt++)
          out[(size_t)gr * NC + nt * 16 + m] = v[nt][i] - sum[i];
      }
    }
  }
}

// ---------------- launch ----------------
extern "C" void kernel_launch(void* const* d_in, const int* in_sizes, int n_in,
                              void* d_out, int out_size, void* d_ws, size_t ws_size,
                              hipStream_t stream) {
  const float* x      = (const float*)d_in[0];
  const int*   ei     = (const int*)d_in[1];
  const float* conv_w = (const float*)d_in[3];
  const float* conv_b = (const float*)d_in[4];
  const float* bn_g   = (const float*)d_in[5];
  const float* bn_b   = (const float*)d_in[6];
  const float* bn_m   = (const float*)d_in[7];
  const float* bn_v   = (const float*)d_in[8];
  const float* fc_w   = (const float*)d_in[9];
  const float* fc_b   = (const float*)d_in[10];
  float* out = (float*)d_out;

  const int* srcI = ei;        // edge_index[0]
  const int* dstI = ei + NE;   // edge_index[1]

  // workspace layout (~92 MiB)
  unsigned short* Xb   = (unsigned short*)d_ws;          // N*H bf16
  unsigned short* Abuf = Xb + (size_t)NN * HF;           // N*H bf16
  unsigned short* Bbuf = Abuf + (size_t)NN * HF;         // N*H bf16
  int* gcur   = (int*)(Bbuf + (size_t)NN * HF);          // NB (+pad)
  int* offs   = gcur + 512;                              // N+4
  int* deg    = offs + 100004;                           // N+4
  unsigned int* binned = (unsigned int*)(deg + 100004);  // NB*BCAP
  int* csr    = (int*)(binned + (size_t)NB * BCAP);      // NB*BCAP
  unsigned short* wt  = (unsigned short*)(csr + (size_t)NB * BCAP); // 6*16384 bf16 (swizzled)
  unsigned short* wtf = wt + 6 * HF * HF;                // 64*128 bf16 (swizzled)
  float* sarr = (float*)(wtf + HF * NC);                 // 6*128
  float* tarr = sarr + 6 * HF;                           // 6*128

  prologue<<<6250, 256, 0, stream>>>(x, Xb, conv_w, conv_b, bn_g, bn_b, bn_m, bn_v,
                                     fc_w, wt, wtf, sarr, tarr, gcur);
  bin_edges<<<NB, 512, 0, stream>>>(srcI, dstI, gcur, binned);
  build_csr<<<NB, 512, 0, stream>>>(binned, gcur, offs, deg, csr);

  aggregate<<<NN / 4, 256, 0, stream>>>(Xb, offs, deg, csr, Abuf);
  mlp3<<<(NN + 127) / 128, 256, 0, stream>>>(Abuf, Bbuf, wt, sarr, tarr);
  aggregate<<<NN / 4, 256, 0, stream>>>(Bbuf, offs, deg, csr, Abuf);
  mlp3fc<<<(NN + 127) / 128, 256, 0, stream>>>(Abuf, out, wt, sarr, tarr, wtf, fc_b);
}

// Round 9
// 332.496 us; speedup vs baseline: 1.1821x; 1.1821x over previous
//
#include <hip/hip_runtime.h>

#define NN 100000
#define NE 1600000
#define HF 128
#define NC 64
#define AP 136      // padded LDS row (bf16 elems): 272B stride, 16B-aligned chunks
#define NB 391      // edge buckets: ceil(100000/256)
#define BSH 8       // 256 nodes per bucket
#define BMASK 255
#define BCAP 4608   // fixed bucket capacity (mean 4096 + 8 sigma)

typedef __bf16 bf16x8 __attribute__((ext_vector_type(8)));
typedef float  f32x4  __attribute__((ext_vector_type(4)));
typedef unsigned short us8 __attribute__((ext_vector_type(8)));

__device__ __forceinline__ unsigned short f2b(float x) {
  unsigned int u = __float_as_uint(x);
  u += 0x7FFFu + ((u >> 16) & 1u);   // RNE
  return (unsigned short)(u >> 16);
}
__device__ __forceinline__ float b2f(unsigned short b) {
  return __uint_as_float(((unsigned int)b) << 16);
}

// ---------------- prologue_bin: cast x->bf16, swizzle weights, init gcur,
//                  AND (blocks < NB) bin edges into fixed-capacity buckets ----
// wt layout (ushort):  ((((ls)*4 + k0)*8 + nt)*64 + q*16 + m)*8 + j
// wtf layout (ushort): (((k0)*4 + nt)*64 + q*16 + m)*8 + j
// binned entry = src (17 bits) | dst_local (8 bits) << 17
__global__ __launch_bounds__(512) void prologue_bin(const float* __restrict__ x,
                                                    unsigned short* __restrict__ xb,
                                                    const float* __restrict__ conv_w,
                                                    const float* __restrict__ conv_b,
                                                    const float* __restrict__ bn_g,
                                                    const float* __restrict__ bn_b,
                                                    const float* __restrict__ bn_m,
                                                    const float* __restrict__ bn_v,
                                                    const float* __restrict__ fc_w,
                                                    unsigned short* __restrict__ wt,
                                                    unsigned short* __restrict__ wtf,
                                                    float* __restrict__ sarr,
                                                    float* __restrict__ tarr,
                                                    int* __restrict__ gcur,
                                                    const int* __restrict__ src,
                                                    const int* __restrict__ dst,
                                                    unsigned int* __restrict__ binned) {
  __shared__ int hist[NB];
  int t = threadIdx.x;
  int idx = blockIdx.x * 512 + t;                 // grid 3125*512 = 1.6M
  // ---- cast: 12.8M floats, 8 per thread ----
  {
    size_t i = (size_t)idx * 8;
    float4 a = *(const float4*)(x + i);
    float4 b = *(const float4*)(x + i + 4);
    us8 v = { f2b(a.x), f2b(a.y), f2b(a.z), f2b(a.w),
              f2b(b.x), f2b(b.y), f2b(b.z), f2b(b.w) };
    *(us8*)(xb + i) = v;
  }
  // ---- weight swizzle + BN fold + gcur init (low blocks only by idx range) ----
  if (idx < 6 * HF * HF) {
    int j  = idx & 7;
    int m  = (idx >> 3) & 15;
    int q  = (idx >> 7) & 3;
    int nt = (idx >> 9) & 7;
    int k0 = (idx >> 12) & 3;
    int ls = idx >> 14;                 // 0..5
    int k = k0 * 32 + q * 8 + j;
    int n = nt * 16 + m;
    wt[idx] = f2b(conv_w[(ls * HF + k) * HF + n]);
  }
  if (idx < HF * NC) {
    int j  = idx & 7;
    int m  = (idx >> 3) & 15;
    int q  = (idx >> 7) & 3;
    int nt = (idx >> 9) & 3;
    int k0 = idx >> 11;                 // 0..3
    int k = k0 * 32 + q * 8 + j;
    int c = nt * 16 + m;
    wtf[idx] = f2b(fc_w[k * NC + c]);
  }
  if (idx < 6 * HF) {
    float s = bn_g[idx] * rsqrtf(bn_v[idx] + 1e-5f);
    sarr[idx] = s;
    tarr[idx] = (conv_b[idx] - bn_m[idx]) * s + bn_b[idx];
  }
  // gcur is initialized by bin blocks below (before use) -- but reservation
  // uses atomicAdd on gcur, so init must be globally visible BEFORE any
  // reservation. Keep it simple: init via the same bin blocks' thread 0..NB-1
  // would race across blocks. Instead init from idx like before (all blocks
  // write before bin phase barrier? No cross-block barrier exists!).
  // => gcur is initialized by a hipMemsetAsync-equivalent: we precompute it
  //    via idx write here is racy vs other blocks' reservations.
  // Resolution: bin blocks reserve via atomicAdd(&gcur[b]) where gcur was
  //    initialized in a PREVIOUS kernel. We instead store per-bucket bases
  //    implicitly: gcur[] holds only the RUNNING COUNT (init 0 by memset),
  //    and binned position = b*BCAP + count. (memset done by host-side
  //    hipMemsetAsync before this kernel.)
  // ---- bin edges (blocks 0..NB-1) ----
  if (blockIdx.x < NB) {
    if (t < NB) hist[t] = 0;
    __syncthreads();
    int base = blockIdx.x * 4096;
    int sv[8], dv[8];
    #pragma unroll
    for (int j = 0; j < 8; j++) {
      int e = base + j * 512 + t;
      bool ok = e < NE;
      dv[j] = ok ? dst[e] : -1;
      sv[j] = ok ? src[e] : 0;
      if (ok) atomicAdd(&hist[dv[j] >> BSH], 1);
    }
    __syncthreads();
    if (t < NB) {
      int c = hist[t];
      if (c) hist[t] = t * BCAP + atomicAdd(&gcur[t], c);   // gcur holds count only
    }
    __syncthreads();
    #pragma unroll
    for (int j = 0; j < 8; j++) {
      if (dv[j] >= 0) {
        int b = dv[j] >> BSH;
        int p = atomicAdd(&hist[b], 1);
        binned[p] = (unsigned int)sv[j] | ((unsigned int)(dv[j] & BMASK) << 17);
      }
    }
  }
}

// ---------------- per-bucket CSR build: offs + deg + csr (L2-local scatter) ----
__global__ __launch_bounds__(512) void build_csr(const unsigned int* __restrict__ binned,
                                                 const int* __restrict__ gcur,
                                                 int* __restrict__ offs,
                                                 int* __restrict__ deg,
                                                 int* __restrict__ csr) {
  __shared__ int ncnt[256];
  __shared__ int sm[256];
  int t = threadIdx.x;
  int b = blockIdx.x;
  int beg = b * BCAP;
  int cntb = gcur[b];                       // gcur holds per-bucket edge count
  if (t < 256) ncnt[t] = 0;
  __syncthreads();
  for (int e = beg + t; e < beg + cntb; e += 512) atomicAdd(&ncnt[binned[e] >> 17], 1);
  __syncthreads();
  int s = 0;
  if (t < 256) { s = ncnt[t]; sm[t] = s; }
  __syncthreads();
  for (int off = 1; off < 256; off <<= 1) {
    int u = (t < 256 && t >= off) ? sm[t - off] : 0;
    __syncthreads();
    if (t < 256) sm[t] += u;
    __syncthreads();
  }
  if (t < 256) {
    int ex = sm[t] - s + beg;
    int node = (b << BSH) + t;
    if (node < NN) { offs[node] = ex; deg[node] = s; }
    ncnt[t] = ex;
  }
  __syncthreads();
  for (int e = beg + t; e < beg + cntb; e += 512) {
    unsigned int u = binned[e];
    int p = atomicAdd(&ncnt[u >> 17], 1);
    csr[p] = (int)(u & 0x1FFFFu);
  }
}

// ---------------- aggregation: hsum[i] = h[i] + sum_{e->i} h[src_e]  (bf16) ----
// 2-way unrolled edge loop: two outstanding 256B row loads per stream.
__global__ __launch_bounds__(256) void aggregate(const unsigned short* __restrict__ h,
                                                 const int* __restrict__ offs,
                                                 const int* __restrict__ deg,
                                                 const int* __restrict__ csr,
                                                 unsigned short* __restrict__ out) {
  int wave = threadIdx.x >> 6;
  int lane = threadIdx.x & 63;
  int node = blockIdx.x * 4 + wave;
  if (node >= NN) return;
  int g  = lane >> 4;     // edge stream 0..3
  int sl = lane & 15;     // 16B column chunk
  int beg = offs[node];
  int dg  = deg[node];

  float acc[8];
  if (g == 0) {
    us8 v = *(const us8*)(h + (size_t)node * HF + sl * 8);
    #pragma unroll
    for (int i = 0; i < 8; i++) acc[i] = b2f(v[i]);
  } else {
    #pragma unroll
    for (int i = 0; i < 8; i++) acc[i] = 0.f;
  }

  int e = beg + g;
  int last = beg + dg;
  for (; e + 4 < last; e += 8) {          // unroll x2: both loads in flight
    int s0 = csr[e];
    int s1 = csr[e + 4];
    us8 v0 = *(const us8*)(h + (size_t)s0 * HF + sl * 8);
    us8 v1 = *(const us8*)(h + (size_t)s1 * HF + sl * 8);
    #pragma unroll
    for (int i = 0; i < 8; i++) acc[i] += b2f(v0[i]);
    #pragma unroll
    for (int i = 0; i < 8; i++) acc[i] += b2f(v1[i]);
  }
  if (e < last) {
    int s0 = csr[e];
    us8 v0 = *(const us8*)(h + (size_t)s0 * HF + sl * 8);
    #pragma unroll
    for (int i = 0; i < 8; i++) acc[i] += b2f(v0[i]);
  }

  #pragma unroll
  for (int i = 0; i < 8; i++) {
    acc[i] += __shfl_xor(acc[i], 16, 64);
    acc[i] += __shfl_xor(acc[i], 32, 64);
  }
  if (g == 0) {
    us8 r;
    #pragma unroll
    for (int i = 0; i < 8; i++) r[i] = f2b(acc[i]);
    *(us8*)(out + (size_t)node * HF + sl * 8) = r;
  }
}

// =======================================================================
// Barrier-free MLP (16 rows/wave, round-7 form): weights direct from global
// (fragment-swizzled, L1/L2-resident); activations wave-private.
// =======================================================================
__device__ __forceinline__ void mlp3_body(const unsigned short* __restrict__ in,
                                          unsigned short* Ab,
                                          const unsigned short* __restrict__ wt,
                                          const float* __restrict__ sarr,
                                          const float* __restrict__ tarr,
                                          int layer, int row0, int wave, int lane,
                                          bf16x8 af[4]) {
  int m = lane & 15, q = lane >> 4;
  int node = row0 + wave * 16 + m;
  int nclamp = (node < NN) ? node : 0;        // OOB rows compute garbage, never stored
  #pragma unroll
  for (int k0 = 0; k0 < 4; k0++)
    af[k0] = *(const bf16x8*)(in + (size_t)nclamp * HF + k0 * 32 + q * 8);

  const unsigned short* wbase = wt + layer * 3 * 16384;   // 16384 ushorts per sub
  #pragma unroll
  for (int sub = 0; sub < 3; sub++) {
    const unsigned short* wsub = wbase + sub * 16384;
    f32x4 acc[8];
    #pragma unroll
    for (int nt = 0; nt < 8; nt++) {
      acc[nt] = (f32x4){0.f, 0.f, 0.f, 0.f};
      #pragma unroll
      for (int k0 = 0; k0 < 4; k0++) {
        bf16x8 bf = *(const bf16x8*)(wsub + ((k0 * 8 + nt) * 64 + lane) * 8);
        acc[nt] = __builtin_amdgcn_mfma_f32_16x16x32_bf16(af[k0], bf, acc[nt], 0, 0, 0);
      }
    }
    const float* sp = sarr + (layer * 3 + sub) * HF;
    const float* tp = tarr + (layer * 3 + sub) * HF;
    #pragma unroll
    for (int nt = 0; nt < 8; nt++) {
      int c = nt * 16 + m;
      float sc = sp[c], sh = tp[c];
      #pragma unroll
      for (int i = 0; i < 4; i++) {
        int r = wave * 16 + q * 4 + i;     // C/D: col=lane&15, row=(lane>>4)*4+i
        float y = fmaxf(acc[nt][i] * sc + sh, 0.f);
        Ab[r * AP + c] = f2b(y);           // own rows: no barrier
      }
    }
    #pragma unroll
    for (int k0 = 0; k0 < 4; k0++)         // reload fragments (wave-local LDS RAW)
      af[k0] = *(const bf16x8*)&Ab[(wave * 16 + m) * AP + k0 * 32 + q * 8];
  }
}

// ---------------- layer-0 MLP: bf16 in -> bf16 out ----------------
__global__ __launch_bounds__(256) void mlp3(const unsigned short* __restrict__ in,
                                            unsigned short* __restrict__ out,
                                            const unsigned short* __restrict__ wt,
                                            const float* __restrict__ sarr,
                                            const float* __restrict__ tarr) {
  __shared__ unsigned short Ab[64 * AP];
  int t = threadIdx.x;
  int lane = t & 63, wave = t >> 6;
  int row0 = blockIdx.x * 64;
  bf16x8 af[4];
  mlp3_body(in, Ab, wt, sarr, tarr, 0, row0, wave, lane, af);

  // wave-local coalesced bf16 store of own 16 rows
  for (int it = 0; it < 4; it++) {
    int idx = it * 64 + lane;              // 4 rows x 16 chunks per pass
    int r = wave * 16 + (idx >> 4);
    int c = (idx & 15) << 3;
    int gr = row0 + r;
    if (gr < NN) *(us8*)(out + (size_t)gr * HF + c) = *(const us8*)&Ab[r * AP + c];
  }
}

// ---------------- layer-1 MLP + FC(128->64) + log_softmax ----------------
__global__ __launch_bounds__(256) void mlp3fc(const unsigned short* __restrict__ in,
                                              float* __restrict__ out,
                                              const unsigned short* __restrict__ wt,
                                              const float* __restrict__ sarr,
                                              const float* __restrict__ tarr,
                                              const unsigned short* __restrict__ wtf,
                                              const float* __restrict__ fc_b) {
  __shared__ unsigned short Ab[64 * AP];
  int t = threadIdx.x;
  int lane = t & 63, wave = t >> 6;
  int row0 = blockIdx.x * 64;
  int m = lane & 15, q = lane >> 4;
  bf16x8 af[4];
  mlp3_body(in, Ab, wt, sarr, tarr, 1, row0, wave, lane, af);

  // ---- FC 128->64 + log_softmax, all in registers ----
  f32x4 acc[4];
  #pragma unroll
  for (int nt = 0; nt < 4; nt++) {
    acc[nt] = (f32x4){0.f, 0.f, 0.f, 0.f};
    #pragma unroll
    for (int k0 = 0; k0 < 4; k0++) {
      bf16x8 bf = *(const bf16x8*)(wtf + ((k0 * 4 + nt) * 64 + lane) * 8);
      acc[nt] = __builtin_amdgcn_mfma_f32_16x16x32_bf16(af[k0], bf, acc[nt], 0, 0, 0);
    }
  }
  // logits: lane (q,m) holds rows q*4+i (i<4), cols nt*16+m
  float v[4][4];
  #pragma unroll
  for (int nt = 0; nt < 4; nt++) {
    float b = fc_b[nt * 16 + m];
    #pragma unroll
    for (int i = 0; i < 4; i++) v[nt][i] = acc[nt][i] + b;
  }
  float mx[4], sum[4];
  #pragma unroll
  for (int i = 0; i < 4; i++) {
    mx[i] = fmaxf(fmaxf(v[0][i], v[1][i]), fmaxf(v[2][i], v[3][i]));
    mx[i] = fmaxf(mx[i], __shfl_xor(mx[i], 1, 64));
    mx[i] = fmaxf(mx[i], __shfl_xor(mx[i], 2, 64));
    mx[i] = fmaxf(mx[i], __shfl_xor(mx[i], 4, 64));
    mx[i] = fmaxf(mx[i], __shfl_xor(mx[i], 8, 64));
    sum[i] = __expf(v[0][i] - mx[i]) + __expf(v[1][i] - mx[i])
           + __expf(v[2][i] - mx[i]) + __expf(v[3][i] - mx[i]);
    sum[i] += __shfl_xor(sum[i], 1, 64);
    sum[i] += __shfl_xor(sum[i], 2, 64);
    sum[i] += __shfl_xor(sum[i], 4, 64);
    sum[i] += __shfl_xor(sum[i], 8, 64);
    sum[i] = __logf(sum[i]) + mx[i];       // logsumexp
  }
  #pragma unroll
  for (int i = 0; i < 4; i++) {
    int gr = row0 + wave * 16 + q * 4 + i;
    if (gr < NN) {
      #pragma unroll
      for (int nt = 0; nt < 4; nt++)
        out[(size_t)gr * NC + nt * 16 + m] = v[nt][i] - sum[i];
    }
  }
}

// ---------------- launch ----------------
extern "C" void kernel_launch(void* const* d_in, const int* in_sizes, int n_in,
                              void* d_out, int out_size, void* d_ws, size_t ws_size,
                              hipStream_t stream) {
  const float* x      = (const float*)d_in[0];
  const int*   ei     = (const int*)d_in[1];
  const float* conv_w = (const float*)d_in[3];
  const float* conv_b = (const float*)d_in[4];
  const float* bn_g   = (const float*)d_in[5];
  const float* bn_b   = (const float*)d_in[6];
  const float* bn_m   = (const float*)d_in[7];
  const float* bn_v   = (const float*)d_in[8];
  const float* fc_w   = (const float*)d_in[9];
  const float* fc_b   = (const float*)d_in[10];
  float* out = (float*)d_out;

  const int* srcI = ei;        // edge_index[0]
  const int* dstI = ei + NE;   // edge_index[1]

  // workspace layout (~92 MiB)
  unsigned short* Xb   = (unsigned short*)d_ws;          // N*H bf16
  unsigned short* Abuf = Xb + (size_t)NN * HF;           // N*H bf16
  unsigned short* Bbuf = Abuf + (size_t)NN * HF;         // N*H bf16
  int* gcur   = (int*)(Bbuf + (size_t)NN * HF);          // NB (+pad) -- counts, memset 0
  int* offs   = gcur + 512;                              // N+4
  int* deg    = offs + 100004;                           // N+4
  unsigned int* binned = (unsigned int*)(deg + 100004);  // NB*BCAP
  int* csr    = (int*)(binned + (size_t)NB * BCAP);      // NB*BCAP
  unsigned short* wt  = (unsigned short*)(csr + (size_t)NB * BCAP); // 6*16384 bf16 (swizzled)
  unsigned short* wtf = wt + 6 * HF * HF;                // 64*128 bf16 (swizzled)
  float* sarr = (float*)(wtf + HF * NC);                 // 6*128
  float* tarr = sarr + 6 * HF;                           // 6*128

  hipMemsetAsync(gcur, 0, sizeof(int) * NB, stream);
  prologue_bin<<<3125, 512, 0, stream>>>(x, Xb, conv_w, conv_b, bn_g, bn_b, bn_m, bn_v,
                                         fc_w, wt, wtf, sarr, tarr, gcur,
                                         srcI, dstI, binned);
  build_csr<<<NB, 512, 0, stream>>>(binned, gcur, offs, deg, csr);

  aggregate<<<NN / 4, 256, 0, stream>>>(Xb, offs, deg, csr, Abuf);
  mlp3<<<(NN + 63) / 64, 256, 0, stream>>>(Abuf, Bbuf, wt, sarr, tarr);
  aggregate<<<NN / 4, 256, 0, stream>>>(Bbuf, offs, deg, csr, Abuf);
  mlp3fc<<<(NN + 63) / 64, 256, 0, stream>>>(Abuf, out, wt, sarr, tarr, wtf, fc_b);
}